// Round 16
// baseline (63.808 us; speedup 1.0000x reference)
//
#include <hip/hip_runtime.h>

#define Nn 256
#define Cc 128
#define Pp 275
#define Dd 128

typedef unsigned int u32;
typedef unsigned short u16;
typedef float f32x4 __attribute__((ext_vector_type(4)));
typedef short bf16x8 __attribute__((ext_vector_type(8)));

__device__ __forceinline__ float bf2f(u16 h) {
    return __uint_as_float(((u32)h) << 16);
}
__device__ __forceinline__ u16 f2bf(float f) {
    u32 u = __float_as_uint(f);
    return (u16)((u + 0x7fffu + ((u >> 16) & 1u)) >> 16);
}

// ---------------- K1: bias_t / bias_p (N x D) + f->bf16 + Wl^T bf16 ----------------
__global__ __launch_bounds__(256) void bias_kernel(
    const float* __restrict__ m_t, const float* __restrict__ m_p,
    const float* __restrict__ c_t, const float* __restrict__ c_p,
    const float* __restrict__ W, const float* __restrict__ b,
    const float* __restrict__ f,
    float* __restrict__ bias_t, float* __restrict__ bias_p,
    u16* __restrict__ f_bf, u16* __restrict__ WlT)
{
    int idx = blockIdx.x * 256 + threadIdx.x;   // N*D = 32768
    int n = idx >> 7, d = idx & 127;
    float at = 0.f, ap = 0.f;
#pragma unroll 8
    for (int k = 0; k < 64; ++k) {
        float wm = W[(128 + k) * 128 + d];
        float wc = W[(192 + k) * 128 + d];
        at = fmaf(m_t[n * 64 + k], wm, at);
        at = fmaf(c_t[n * 64 + k], wc, at);
        ap = fmaf(m_p[n * 64 + k], wm, ap);
        ap = fmaf(c_p[n * 64 + k], wc, ap);
    }
    float bb = b[d];
    bias_t[idx] = at + bb;
    bias_p[idx] = ap + bb;
    f_bf[idx] = f2bf(f[idx]);
    if (idx < 16384) {                 // WlT[d][c] = Wl[c][d]
        int dd = idx >> 7, cc = idx & 127;
        WlT[idx] = f2bf(W[cc * 128 + dd]);
    }
}

// ---------------- K2: join — p-half stage, one barrier, B in regs, 4 blocks/CU -----
// grid (4, 256): blockIdx.x = pass*2 + phalf; block = 512 thr = 8 waves; wave w: dt=w.
// Stage: x_pass[n][c][phalf-range] fp32 -> LDS [lp][c] bf16 (local rows),
//   swizzle col = 2c ^ ((lp&7)<<4) ^ (((lp>>3)&1)<<5).
// Compute: 9 p-tiles x 4 chained MFMA; global tile 17 re-anchored at p0=259.
__global__ __launch_bounds__(512) void join_half_kernel(
    const float* __restrict__ x_t, const float* __restrict__ x_p,
    const u16* __restrict__ WlT,
    const float* __restrict__ bias_t, const float* __restrict__ bias_p,
    u16* __restrict__ pred, u16* __restrict__ pos)
{
    __shared__ u16 xlds[144 * 128];          // 36,864 B
    const int tid = threadIdx.x;
    const int pass = blockIdx.x >> 1;
    const int phalf = blockIdx.x & 1;
    const int n = blockIdx.y;
    const int w = tid >> 6;
    const int l = tid & 63;
    const int g = l >> 4;

    const float* sx = (pass ? x_p : x_t) + (size_t)n * (Cc * Pp);
    u16* outp = pass ? pos : pred;

    // B-frags in registers: wave w -> WlT rows w*16..w*16+15 (constant over tiles)
    bf16x8 B[4];
    {
        const int row = w * 16 + (l & 15);
#pragma unroll
        for (int kk = 0; kk < 4; ++kk)
            B[kk] = *reinterpret_cast<const bf16x8*>(
                (const char*)WlT + row * 256 + kk * 64 + g * 16);
    }
    const float bv = (pass ? bias_p : bias_t)[n * 128 + w * 16 + (l & 15)];

    const int pbase = phalf * 144;           // global p of local row 0
    const int NQ = phalf ? 33 : 36;          // local 4-row quads to stage

    // stage: thread = (c-pair tid>>3, j = tid&7); local quads q = j, j+8, ...
    {
        const int c0 = (tid >> 3) * 2;
        const int j = tid & 7;
        const float* r0p = sx + (size_t)c0 * Pp + pbase;
        const float* r1p = r0p + Pp;
        for (int q = j; q < NQ; q += 8) {
            const int lp0 = 4 * q;
            float v0[4], v1[4];
            if (pbase + lp0 + 3 < Pp) {
                f32x4 t0 = *reinterpret_cast<const f32x4*>(r0p + lp0);
                f32x4 t1 = *reinterpret_cast<const f32x4*>(r1p + lp0);
#pragma unroll
                for (int e = 0; e < 4; ++e) { v0[e] = t0[e]; v1[e] = t1[e]; }
            } else {
#pragma unroll
                for (int e = 0; e < 4; ++e) {
                    int pe = pbase + lp0 + e;
                    if (pe > Pp - 1) pe = Pp - 1;
                    pe -= pbase;
                    v0[e] = r0p[pe]; v1[e] = r1p[pe];
                }
            }
#pragma unroll
            for (int e = 0; e < 4; ++e) {
                const int lp = lp0 + e;
                const int col = (c0 * 2) ^ ((lp & 7) << 4) ^ (((lp >> 3) & 1) << 5);
                *reinterpret_cast<u32*>((char*)xlds + lp * 256 + col) =
                    (u32)f2bf(v0[e]) | ((u32)f2bf(v1[e]) << 16);
            }
        }
    }
    __syncthreads();

    const int d = w * 16 + (l & 15);
#pragma unroll
    for (int t = 0; t < 9; ++t) {
        const int tg = phalf * 9 + t;
        const int p0 = (tg < 17) ? tg * 16 : 259;
        const int lrow = p0 - pbase + (l & 15);
        bf16x8 A[4];
#pragma unroll
        for (int kk = 0; kk < 4; ++kk) {
            const int col = (kk * 64 + g * 16) ^ ((lrow & 7) << 4) ^ (((lrow >> 3) & 1) << 5);
            A[kk] = *reinterpret_cast<const bf16x8*>((const char*)xlds + lrow * 256 + col);
        }
        f32x4 acc = {0.f, 0.f, 0.f, 0.f};
#pragma unroll
        for (int kk = 0; kk < 4; ++kk)
            acc = __builtin_amdgcn_mfma_f32_16x16x32_bf16(A[kk], B[kk], acc, 0, 0, 0);
#pragma unroll
        for (int r = 0; r < 4; ++r) {
            const int p = p0 + g * 4 + r;      // < Pp by construction
            outp[((size_t)p * Nn + n) * Dd + d] = f2bf(acc[r] + bv);
        }
    }
}

// ---------------- K3: logits partial — m-half split, 32 KB stage (R14 exact) ------
__global__ __launch_bounds__(512) void logits_part_kernel(
    const u16* __restrict__ f_bf,
    const u16* __restrict__ pred, const u16* __restrict__ pos,
    float* __restrict__ spart, float* __restrict__ dgarr)
{
    __shared__ u16 lds[128 * Dd];   // 32 KB swizzled pos[p] m-half tile
    const int tid = threadIdx.x;
    const int sel = blockIdx.x >> 1;
    const int mhalf = blockIdx.x & 1;
    const int p = blockIdx.y;
    const int w = tid >> 6;
    const int l = tid & 63;
    const int r0 = w * 32;

    {
        const uint4* src = reinterpret_cast<const uint4*>(
            pos + (size_t)p * (Nn * Dd) + (size_t)mhalf * 128 * Dd);
#pragma unroll
        for (int it = 0; it < 4; ++it) {
            int j = tid + 512 * it;
            int row = j >> 4;
            int colb = (j & 15) << 4;
            uint4 v = src[j];
            *reinterpret_cast<uint4*>((char*)lds + row * 256 + (colb ^ ((row & 7) << 4))) = v;
        }
    }

    const u16* Abase = sel ? (pred + (size_t)p * (Nn * Dd)) : f_bf;
    bf16x8 A[2][4];
    {
        const int arow = l & 15;
        const int acol = (l >> 4) << 4;
#pragma unroll
        for (int rt = 0; rt < 2; ++rt)
#pragma unroll
            for (int kk = 0; kk < 4; ++kk) {
                const char* ap = (const char*)Abase
                               + (size_t)(r0 + rt * 16 + arow) * 256 + kk * 64 + acol;
                A[rt][kk] = *reinterpret_cast<const bf16x8*>(ap);
            }
    }

    __syncthreads();

    const float L2E = 1.4426950408889634f;
    float s_[2][4];
    float dg[2][4];
#pragma unroll
    for (int rt = 0; rt < 2; ++rt)
#pragma unroll
        for (int r = 0; r < 4; ++r) { s_[rt][r] = 0.f; dg[rt][r] = 0.f; }

    const int mcol = l & 15;
    const int bcol = (l >> 4) << 4;

    for (int ctl = 0; ctl < 8; ++ctl) {            // global ct = mhalf*8 + ctl
        bf16x8 B[4];
        const int mrow = ctl * 16 + mcol;
#pragma unroll
        for (int kk = 0; kk < 4; ++kk) {
            int cb = kk * 64 + bcol;
            B[kk] = *reinterpret_cast<const bf16x8*>(
                (const char*)lds + mrow * 256 + (cb ^ ((mrow & 7) << 4)));
        }
#pragma unroll
        for (int rt = 0; rt < 2; ++rt) {
            f32x4 acc = {0.f, 0.f, 0.f, 0.f};
#pragma unroll
            for (int kk = 0; kk < 4; ++kk)
                acc = __builtin_amdgcn_mfma_f32_16x16x32_bf16(A[rt][kk], B[kk], acc, 0, 0, 0);
            const bool isdg_ct = ((mhalf * 8 + ctl) == ((r0 >> 4) + rt));
#pragma unroll
            for (int r = 0; r < 4; ++r) {
                float v = acc[r];
                s_[rt][r] += __builtin_amdgcn_exp2f(fmaf(v, L2E, -64.f));
                if (isdg_ct && ((l & 15) == (((l >> 4) << 2) + r))) dg[rt][r] = v;
            }
        }
    }

    float* sp = spart + (((size_t)(sel * Pp + p) * 2 + mhalf) << 8);
    float* dp = dgarr + (((size_t)(sel * Pp + p)) << 8);
    const bool owns_dg = ((w >> 2) == mhalf);
#pragma unroll
    for (int rt = 0; rt < 2; ++rt)
#pragma unroll
        for (int r = 0; r < 4; ++r) {
            float s = s_[rt][r];
            s += __shfl_xor(s, 1);
            s += __shfl_xor(s, 2);
            s += __shfl_xor(s, 4);
            s += __shfl_xor(s, 8);
            if ((l & 15) == (((l >> 4) << 2) + r)) {
                const int nn = r0 + rt * 16 + ((l >> 4) << 2) + r;
                sp[nn] = s;
                if (owns_dg) dp[nn] = dg[rt][r];
            }
        }
}

// ---------------- K3b: merge m-half partials -> per-(sel,p) sum ----------------
__global__ __launch_bounds__(256) void merge_kernel(
    const float* __restrict__ spart, const float* __restrict__ dgarr,
    float* __restrict__ partial)
{
    __shared__ float red[256];
    const int sel = blockIdx.x;
    const int p = blockIdx.y;
    const int n = threadIdx.x;
    const size_t base = ((size_t)(sel * Pp + p) * 2) << 8;
    float s = spart[base + n] + spart[base + 256 + n];
    float dgv = dgarr[(((size_t)(sel * Pp + p)) << 8) + n];
    float val = 0.6931471805599453f * (64.f + __log2f(s)) - dgv;
    red[n] = val;
    __syncthreads();
    for (int k = 128; k > 0; k >>= 1) {
        if (n < k) red[n] += red[n + k];
        __syncthreads();
    }
    if (n == 0) partial[sel * Pp + p] = red[0];
}

// ---------------- K4: deterministic final reduce ----------------
__global__ __launch_bounds__(256) void reduce_kernel(
    const float* __restrict__ partial, float* __restrict__ out)
{
    __shared__ float red[256];
    float s = 0.f;
    for (int i = threadIdx.x; i < 2 * Pp; i += 256) s += partial[i];
    red[threadIdx.x] = s;
    __syncthreads();
    for (int k = 128; k > 0; k >>= 1) {
        if (threadIdx.x < k) red[threadIdx.x] += red[threadIdx.x + k];
        __syncthreads();
    }
    if (threadIdx.x == 0) out[0] = red[0] * (1.0f / (Pp * (float)Nn));
}

extern "C" void kernel_launch(void* const* d_in, const int* in_sizes, int n_in,
                              void* d_out, int out_size, void* d_ws, size_t ws_size,
                              hipStream_t stream)
{
    const float* f   = (const float*)d_in[0];
    const float* x_t = (const float*)d_in[1];
    const float* x_p = (const float*)d_in[2];
    const float* m_t = (const float*)d_in[3];
    const float* m_p = (const float*)d_in[4];
    const float* c_t = (const float*)d_in[5];
    const float* c_p = (const float*)d_in[6];
    const float* W   = (const float*)d_in[7];
    const float* b   = (const float*)d_in[8];

    char* ws = (char*)d_ws;
    const size_t SLAB = (size_t)Pp * Nn * Dd;     // 9,011,200 elems

    float* bias_t = (float*)ws;                          // 131072 B
    float* bias_p = bias_t + Nn * Dd;                    // 131072 B
    u16* f_bf = (u16*)(ws + 262144);                     // 65536 B
    u16* WlT  = f_bf + Nn * Dd;                          // 32768 B
    u16* pred = (u16*)(ws + 360448);
    u16* pos  = pred + SLAB;
    float* partial = (float*)(pos + SLAB);               // 550 floats
    float* spart   = partial + 2 * Pp;                   // 2*Pp*2*256 floats
    float* dgarr   = spart + (size_t)2 * Pp * 2 * 256;   // 2*Pp*256 floats

    bias_kernel<<<dim3(Nn * Dd / 256), 256, 0, stream>>>(m_t, m_p, c_t, c_p, W, b, f,
                                                         bias_t, bias_p, f_bf, WlT);
    join_half_kernel<<<dim3(4, Nn), 512, 0, stream>>>(x_t, x_p, WlT, bias_t, bias_p,
                                                      pred, pos);
    logits_part_kernel<<<dim3(4, Pp), 512, 0, stream>>>(f_bf, pred, pos, spart, dgarr);
    merge_kernel<<<dim3(2, Pp), 256, 0, stream>>>(spart, dgarr, partial);
    reduce_kernel<<<1, 256, 0, stream>>>(partial, (float*)d_out);
}

// Round 17
// 61.857 us; speedup vs baseline: 1.0315x; 1.0315x over previous
//
#include <hip/hip_runtime.h>

#define Nn 256
#define Cc 128
#define Pp 275
#define Dd 128

typedef unsigned int u32;
typedef unsigned short u16;
typedef float f32x4 __attribute__((ext_vector_type(4)));
typedef short bf16x8 __attribute__((ext_vector_type(8)));

__device__ __forceinline__ float bf2f(u16 h) {
    return __uint_as_float(((u32)h) << 16);
}
__device__ __forceinline__ u16 f2bf(float f) {
    u32 u = __float_as_uint(f);
    return (u16)((u + 0x7fffu + ((u >> 16) & 1u)) >> 16);
}

// ---------------- K1: bias_t / bias_p (N x D) + f->bf16 + Wl^T bf16 ----------------
__global__ __launch_bounds__(256) void bias_kernel(
    const float* __restrict__ m_t, const float* __restrict__ m_p,
    const float* __restrict__ c_t, const float* __restrict__ c_p,
    const float* __restrict__ W, const float* __restrict__ b,
    const float* __restrict__ f,
    float* __restrict__ bias_t, float* __restrict__ bias_p,
    u16* __restrict__ f_bf, u16* __restrict__ WlT)
{
    int idx = blockIdx.x * 256 + threadIdx.x;   // N*D = 32768
    int n = idx >> 7, d = idx & 127;
    float at = 0.f, ap = 0.f;
#pragma unroll 8
    for (int k = 0; k < 64; ++k) {
        float wm = W[(128 + k) * 128 + d];
        float wc = W[(192 + k) * 128 + d];
        at = fmaf(m_t[n * 64 + k], wm, at);
        at = fmaf(c_t[n * 64 + k], wc, at);
        ap = fmaf(m_p[n * 64 + k], wm, ap);
        ap = fmaf(c_p[n * 64 + k], wc, ap);
    }
    float bb = b[d];
    bias_t[idx] = at + bb;
    bias_p[idx] = ap + bb;
    f_bf[idx] = f2bf(f[idx]);
    if (idx < 16384) {                 // WlT[d][c] = Wl[c][d]
        int dd = idx >> 7, cc = idx & 127;
        WlT[idx] = f2bf(W[cc * 128 + dd]);
    }
}

// ---------------- K2: join — full-n stage (hoisted loads), one barrier, B in regs ---
// grid (2, 256): block = (pass, n); 512 thr = 8 waves; wave w owns dt = w.
// Stage: ALL 18 f32x4 loads issued before any convert (compile-time unroll, ~72 VGPR),
// then fence, then cvt+swizzled LDS writes. One __syncthreads. 18 tiles x 4 MFMA.
__global__ __launch_bounds__(512) void join_full_kernel(
    const float* __restrict__ x_t, const float* __restrict__ x_p,
    const u16* __restrict__ WlT,
    const float* __restrict__ bias_t, const float* __restrict__ bias_p,
    u16* __restrict__ pred, u16* __restrict__ pos)
{
    __shared__ u16 xlds[275 * 128];          // 70,400 B
    const int tid = threadIdx.x;
    const int pass = blockIdx.x;
    const int n = blockIdx.y;
    const int w = tid >> 6;
    const int l = tid & 63;
    const int g = l >> 4;

    const float* sx = (pass ? x_p : x_t) + (size_t)n * (Cc * Pp);
    u16* outp = pass ? pos : pred;

    // B-frags in registers: wave w -> WlT rows w*16..w*16+15 (constant over tiles)
    bf16x8 B[4];
    {
        const int row = w * 16 + (l & 15);
#pragma unroll
        for (int kk = 0; kk < 4; ++kk)
            B[kk] = *reinterpret_cast<const bf16x8*>(
                (const char*)WlT + row * 256 + kk * 64 + g * 16);
    }
    const float bv = (pass ? bias_p : bias_t)[n * 128 + w * 16 + (l & 15)];

    // ---- stage phase: thread = (c-pair tid>>3, j = tid&7); quads q = j+8i ----
    {
        const int c0 = (tid >> 3) * 2;
        const int j = tid & 7;
        const float* r0p = sx + (size_t)c0 * Pp;
        const float* r1p = r0p + Pp;

        f32x4 v0[9], v1[9];
        // issue ALL loads first (static indices -> registers; high MLP)
#pragma unroll
        for (int i = 0; i < 9; ++i) {
            const int q = j + 8 * i;
            if (q < 68) {
                v0[i] = *reinterpret_cast<const f32x4*>(r0p + 4 * q);
                v1[i] = *reinterpret_cast<const f32x4*>(r1p + 4 * q);
            } else if (q == 68) {
                f32x4 a, c;
#pragma unroll
                for (int e = 0; e < 4; ++e) {
                    int pe = 4 * 68 + e; if (pe > Pp - 1) pe = Pp - 1;
                    a[e] = r0p[pe]; c[e] = r1p[pe];
                }
                v0[i] = a; v1[i] = c;
            }
        }
        asm volatile("" ::: "memory");   // keep loads hoisted above converts
        // convert + pack + swizzled LDS write
#pragma unroll
        for (int i = 0; i < 9; ++i) {
            const int q = j + 8 * i;
            if (q < 69) {
#pragma unroll
                for (int e = 0; e < 4; ++e) {
                    int p = 4 * q + e; if (p > Pp - 1) p = Pp - 1;
                    const int col = (c0 * 2) ^ ((p & 7) << 4) ^ (((p >> 3) & 1) << 5);
                    *reinterpret_cast<u32*>((char*)xlds + p * 256 + col) =
                        (u32)f2bf(v0[i][e]) | ((u32)f2bf(v1[i][e]) << 16);
                }
            }
        }
    }
    __syncthreads();

    const int d = w * 16 + (l & 15);
#pragma unroll
    for (int t = 0; t < 18; ++t) {
        const int p0 = (t < 17) ? t * 16 : 259;
        const int arow = p0 + (l & 15);
        bf16x8 A[4];
#pragma unroll
        for (int kk = 0; kk < 4; ++kk) {
            const int col = (kk * 64 + g * 16) ^ ((arow & 7) << 4) ^ (((arow >> 3) & 1) << 5);
            A[kk] = *reinterpret_cast<const bf16x8*>((const char*)xlds + arow * 256 + col);
        }
        f32x4 acc = {0.f, 0.f, 0.f, 0.f};
#pragma unroll
        for (int kk = 0; kk < 4; ++kk)
            acc = __builtin_amdgcn_mfma_f32_16x16x32_bf16(A[kk], B[kk], acc, 0, 0, 0);
#pragma unroll
        for (int r = 0; r < 4; ++r) {
            const int p = p0 + g * 4 + r;      // < Pp by construction
            outp[((size_t)p * Nn + n) * Dd + d] = f2bf(acc[r] + bv);
        }
    }
}

// ---------------- K3: logits partial — m-half split, 32 KB stage (R14 exact) ------
__global__ __launch_bounds__(512) void logits_part_kernel(
    const u16* __restrict__ f_bf,
    const u16* __restrict__ pred, const u16* __restrict__ pos,
    float* __restrict__ spart, float* __restrict__ dgarr)
{
    __shared__ u16 lds[128 * Dd];   // 32 KB swizzled pos[p] m-half tile
    const int tid = threadIdx.x;
    const int sel = blockIdx.x >> 1;
    const int mhalf = blockIdx.x & 1;
    const int p = blockIdx.y;
    const int w = tid >> 6;
    const int l = tid & 63;
    const int r0 = w * 32;

    {
        const uint4* src = reinterpret_cast<const uint4*>(
            pos + (size_t)p * (Nn * Dd) + (size_t)mhalf * 128 * Dd);
#pragma unroll
        for (int it = 0; it < 4; ++it) {
            int j = tid + 512 * it;
            int row = j >> 4;
            int colb = (j & 15) << 4;
            uint4 v = src[j];
            *reinterpret_cast<uint4*>((char*)lds + row * 256 + (colb ^ ((row & 7) << 4))) = v;
        }
    }

    const u16* Abase = sel ? (pred + (size_t)p * (Nn * Dd)) : f_bf;
    bf16x8 A[2][4];
    {
        const int arow = l & 15;
        const int acol = (l >> 4) << 4;
#pragma unroll
        for (int rt = 0; rt < 2; ++rt)
#pragma unroll
            for (int kk = 0; kk < 4; ++kk) {
                const char* ap = (const char*)Abase
                               + (size_t)(r0 + rt * 16 + arow) * 256 + kk * 64 + acol;
                A[rt][kk] = *reinterpret_cast<const bf16x8*>(ap);
            }
    }

    __syncthreads();

    const float L2E = 1.4426950408889634f;
    float s_[2][4];
    float dg[2][4];
#pragma unroll
    for (int rt = 0; rt < 2; ++rt)
#pragma unroll
        for (int r = 0; r < 4; ++r) { s_[rt][r] = 0.f; dg[rt][r] = 0.f; }

    const int mcol = l & 15;
    const int bcol = (l >> 4) << 4;

    for (int ctl = 0; ctl < 8; ++ctl) {            // global ct = mhalf*8 + ctl
        bf16x8 B[4];
        const int mrow = ctl * 16 + mcol;
#pragma unroll
        for (int kk = 0; kk < 4; ++kk) {
            int cb = kk * 64 + bcol;
            B[kk] = *reinterpret_cast<const bf16x8*>(
                (const char*)lds + mrow * 256 + (cb ^ ((mrow & 7) << 4)));
        }
#pragma unroll
        for (int rt = 0; rt < 2; ++rt) {
            f32x4 acc = {0.f, 0.f, 0.f, 0.f};
#pragma unroll
            for (int kk = 0; kk < 4; ++kk)
                acc = __builtin_amdgcn_mfma_f32_16x16x32_bf16(A[rt][kk], B[kk], acc, 0, 0, 0);
            const bool isdg_ct = ((mhalf * 8 + ctl) == ((r0 >> 4) + rt));
#pragma unroll
            for (int r = 0; r < 4; ++r) {
                float v = acc[r];
                s_[rt][r] += __builtin_amdgcn_exp2f(fmaf(v, L2E, -64.f));
                if (isdg_ct && ((l & 15) == (((l >> 4) << 2) + r))) dg[rt][r] = v;
            }
        }
    }

    float* sp = spart + (((size_t)(sel * Pp + p) * 2 + mhalf) << 8);
    float* dp = dgarr + (((size_t)(sel * Pp + p)) << 8);
    const bool owns_dg = ((w >> 2) == mhalf);
#pragma unroll
    for (int rt = 0; rt < 2; ++rt)
#pragma unroll
        for (int r = 0; r < 4; ++r) {
            float s = s_[rt][r];
            s += __shfl_xor(s, 1);
            s += __shfl_xor(s, 2);
            s += __shfl_xor(s, 4);
            s += __shfl_xor(s, 8);
            if ((l & 15) == (((l >> 4) << 2) + r)) {
                const int nn = r0 + rt * 16 + ((l >> 4) << 2) + r;
                sp[nn] = s;
                if (owns_dg) dp[nn] = dg[rt][r];
            }
        }
}

// ---------------- K3b: merge m-half partials -> per-(sel,p) sum ----------------
__global__ __launch_bounds__(256) void merge_kernel(
    const float* __restrict__ spart, const float* __restrict__ dgarr,
    float* __restrict__ partial)
{
    __shared__ float red[256];
    const int sel = blockIdx.x;
    const int p = blockIdx.y;
    const int n = threadIdx.x;
    const size_t base = ((size_t)(sel * Pp + p) * 2) << 8;
    float s = spart[base + n] + spart[base + 256 + n];
    float dgv = dgarr[(((size_t)(sel * Pp + p)) << 8) + n];
    float val = 0.6931471805599453f * (64.f + __log2f(s)) - dgv;
    red[n] = val;
    __syncthreads();
    for (int k = 128; k > 0; k >>= 1) {
        if (n < k) red[n] += red[n + k];
        __syncthreads();
    }
    if (n == 0) partial[sel * Pp + p] = red[0];
}

// ---------------- K4: deterministic final reduce ----------------
__global__ __launch_bounds__(256) void reduce_kernel(
    const float* __restrict__ partial, float* __restrict__ out)
{
    __shared__ float red[256];
    float s = 0.f;
    for (int i = threadIdx.x; i < 2 * Pp; i += 256) s += partial[i];
    red[threadIdx.x] = s;
    __syncthreads();
    for (int k = 128; k > 0; k >>= 1) {
        if (threadIdx.x < k) red[threadIdx.x] += red[threadIdx.x + k];
        __syncthreads();
    }
    if (threadIdx.x == 0) out[0] = red[0] * (1.0f / (Pp * (float)Nn));
}

extern "C" void kernel_launch(void* const* d_in, const int* in_sizes, int n_in,
                              void* d_out, int out_size, void* d_ws, size_t ws_size,
                              hipStream_t stream)
{
    const float* f   = (const float*)d_in[0];
    const float* x_t = (const float*)d_in[1];
    const float* x_p = (const float*)d_in[2];
    const float* m_t = (const float*)d_in[3];
    const float* m_p = (const float*)d_in[4];
    const float* c_t = (const float*)d_in[5];
    const float* c_p = (const float*)d_in[6];
    const float* W   = (const float*)d_in[7];
    const float* b   = (const float*)d_in[8];

    char* ws = (char*)d_ws;
    const size_t SLAB = (size_t)Pp * Nn * Dd;     // 9,011,200 elems

    float* bias_t = (float*)ws;                          // 131072 B
    float* bias_p = bias_t + Nn * Dd;                    // 131072 B
    u16* f_bf = (u16*)(ws + 262144);                     // 65536 B
    u16* WlT  = f_bf + Nn * Dd;                          // 32768 B
    u16* pred = (u16*)(ws + 360448);
    u16* pos  = pred + SLAB;
    float* partial = (float*)(pos + SLAB);               // 550 floats
    float* spart   = partial + 2 * Pp;                   // 2*Pp*2*256 floats
    float* dgarr   = spart + (size_t)2 * Pp * 2 * 256;   // 2*Pp*256 floats

    bias_kernel<<<dim3(Nn * Dd / 256), 256, 0, stream>>>(m_t, m_p, c_t, c_p, W, b, f,
                                                         bias_t, bias_p, f_bf, WlT);
    join_full_kernel<<<dim3(2, Nn), 512, 0, stream>>>(x_t, x_p, WlT, bias_t, bias_p,
                                                      pred, pos);
    logits_part_kernel<<<dim3(4, Pp), 512, 0, stream>>>(f_bf, pred, pos, spart, dgarr);
    merge_kernel<<<dim3(2, Pp), 256, 0, stream>>>(spart, dgarr, partial);
    reduce_kernel<<<1, 256, 0, stream>>>(partial, (float*)d_out);
}